// Round 16
// baseline (779.929 us; speedup 1.0000x reference)
//
#include <hip/hip_runtime.h>
#include <math.h>

// ---------------------------------------------------------------------------
// TemporalUnitRolloutV341 — GRU rollout, 32 steps over 2048 rows of D=512.
// R16 = R15 with compile fixes:
//   - no LDS pointer arrays (addrspacecast static-init error): buffers are
//     addressed as smem + (buf << 14)
//   - gates VGPR trim (drop pre_hf preload) to meet __launch_bounds__(256,4)
// Gates: BK=32 dbuf (R14-verified layout), T3-min schedule (stage(kt+1) ->
// compute(kt) -> 1 barrier, 16 barriers total), r/z gates bf16x2 (A-lo and
// W-lo dropped, sigmoid-damped), n-gate full bf16x3.
// ---------------------------------------------------------------------------

typedef unsigned short u16;
using bf16x8 = __attribute__((ext_vector_type(8))) short;
using f32x4  = __attribute__((ext_vector_type(4))) float;

#define DEV __device__ __forceinline__

constexpr int D   = 512;
constexpr int D3  = 1536;
constexpr int H   = 32;
constexpr int BU  = 2048;
constexpr long long OUT_HALF = (long long)BU * H * D;

DEV u16 f2bf(float x){
  union { float f; unsigned u; } c; c.f = x;
  unsigned u = c.u;
  u += 0x7fffu + ((u >> 16) & 1u);
  return (u16)(u >> 16);
}
DEV float bf2f(u16 b){
  union { unsigned u; float f; } c; c.u = ((unsigned)b) << 16; return c.f;
}

DEV void gload_lds16(const void* g, void* l){
  __builtin_amdgcn_global_load_lds(
      (const __attribute__((address_space(1))) void*)g,
      (__attribute__((address_space(3))) void*)l, 16, 0, 0);
}

DEV f32x4 mfma16(bf16x8 a, bf16x8 b, f32x4 c){
  return __builtin_amdgcn_mfma_f32_16x16x32_bf16(a, b, c, 0, 0, 0);
}

DEV float fsigm(float x){ return 1.f / (1.f + __expf(-x)); }
DEV float ftanh(float x){ return 1.f - 2.f / (1.f + __expf(2.f * x)); }

// ---------------------------------------------------------------------------
// prep: hi/lo splits, W1s, W1g, c1/c2p/d1/d2, Tg, initial state.
// ---------------------------------------------------------------------------
__global__ __launch_bounds__(256) void prep_kernel(
    const float* __restrict__ z_dyn, const float* __restrict__ z_sem,
    const float* __restrict__ te_w,  const float* __restrict__ w_ih,
    const float* __restrict__ w_hh,  const float* __restrict__ ln_g,
    const float* __restrict__ ln_b,  const float* __restrict__ ln2_g,
    const float* __restrict__ ln2_b, const float* __restrict__ w1,
    const float* __restrict__ b1,    const float* __restrict__ w2,
    float* __restrict__ h1, u16* __restrict__ hbh2, u16* __restrict__ hbl2,
    u16* __restrict__ sem_hi, u16* __restrict__ sem_lo,
    u16* __restrict__ wih_hi, u16* __restrict__ wih_lo,
    u16* __restrict__ whh_hi, u16* __restrict__ whh_lo,
    u16* __restrict__ W1s, u16* __restrict__ W1g, u16* __restrict__ w2bf,
    float* __restrict__ c1, float* __restrict__ c2p,
    float* __restrict__ d1, float* __restrict__ d2, float* __restrict__ Tg)
{
  int i = blockIdx.x * 256 + threadIdx.x;
  if (i < BU * D) {
    float hv = z_dyn[i];
    h1[i] = hv;
    u16 hh = f2bf(hv);
    hbh2[i] = hh;
    hbl2[i] = f2bf(hv - bf2f(hh));
    float sv = z_sem[i];
    u16 sh_ = f2bf(sv);
    sem_hi[i] = sh_;
    sem_lo[i] = f2bf(sv - bf2f(sh_));
  }
  if (i < D3 * D) {
    float wv = w_ih[i];
    u16 wh = f2bf(wv);
    wih_hi[i] = wh;
    wih_lo[i] = f2bf(wv - bf2f(wh));
    float uv = w_hh[i];
    u16 uh = f2bf(uv);
    whh_hi[i] = uh;
    whh_lo[i] = f2bf(uv - bf2f(uh));
  }
  if (i < D * D) {
    int k = i >> 9, j = i & 511;
    W1s[i]  = f2bf(w1[k * 1024 + j] * ln2_g[j]);
    w2bf[i] = f2bf(w2[i]);
  }
  if (i < D * 64) {
    int r = i >> 6, ln = i & 63;
    float sc1 = 0.f, sc2 = 0.f, sd1 = 0.f, sd2 = 0.f;
    #pragma unroll
    for (int jj = 0; jj < 8; ++jj) {
      int j = jj * 64 + ln;
      float wA = w1[r * 1024 + j];
      float wB = w1[r * 1024 + 512 + j];
      sc1 += wA * ln2_g[j] + wB * ln2_g[512 + j];
      sc2 += wA * ln2_b[j] + wB * ln2_b[512 + j];
      float wBg = wB * ln2_g[512 + j];
      float wg = wBg * ln_g[j];
      sd1 += wg;
      sd2 += wBg * ln_b[j];
      W1g[r * 512 + j] = f2bf(wg);
    }
    #pragma unroll
    for (int o = 1; o < 64; o <<= 1) {
      sc1 += __shfl_xor(sc1, o); sc2 += __shfl_xor(sc2, o);
      sd1 += __shfl_xor(sd1, o); sd2 += __shfl_xor(sd2, o);
    }
    if (ln == 0) {
      c1[r] = sc1;
      c2p[r] = sc2 + b1[r];
      d1[r] = sd1;
      d2[r] = sd2;
    }
  }
  if (i < H * D3) {
    int c = i >> 5, t = i & 31;
    float s = 0.f;
    for (int d0 = 0; d0 < D; ++d0) s += te_w[t * D + d0] * w_ih[c * D + d0];
    Tg[t * D3 + c] = s;
  }
}

// Per-row sums of sem and sem^2 (ln2 stats split). One wave per row.
__global__ __launch_bounds__(256) void rowstats_kernel(
    const float* __restrict__ sem, float* __restrict__ Ssem,
    float* __restrict__ Ssem2)
{
  const int wid = threadIdx.x >> 6, lane = threadIdx.x & 63;
  const int row = blockIdx.x * 4 + wid;
  const float* p = sem + (size_t)row * D + lane * 8;
  float4 a0 = *(const float4*)p;
  float4 a1 = *(const float4*)(p + 4);
  float s  = a0.x + a0.y + a0.z + a0.w + a1.x + a1.y + a1.z + a1.w;
  float s2 = a0.x*a0.x + a0.y*a0.y + a0.z*a0.z + a0.w*a0.w
           + a1.x*a1.x + a1.y*a1.y + a1.z*a1.z + a1.w*a1.w;
  #pragma unroll
  for (int o = 1; o < 64; o <<= 1) { s += __shfl_xor(s, o); s2 += __shfl_xor(s2, o); }
  if (lane == 0) { Ssem[row] = s; Ssem2[row] = s2; }
}

// ---------------------------------------------------------------------------
// Setup GEMMs: grid (32, 32). by<24 -> G0 tile (bf16x3, +b_ih);
// by>=24 -> Psem tile (plain bf16). 64x64 NT, single-buffered 32KB LDS.
// ---------------------------------------------------------------------------
__global__ __launch_bounds__(256) void setup_kernel(
    const u16* __restrict__ sem_hi, const u16* __restrict__ sem_lo,
    const u16* __restrict__ wih_hi, const u16* __restrict__ wih_lo,
    const u16* __restrict__ W1s, float* __restrict__ G0,
    float* __restrict__ Psem, const float* __restrict__ b_ih)
{
  __shared__ __align__(16) char smem[32768];
  char* Ah = smem;
  char* Al = smem + 8192;
  char* Bh = smem + 16384;
  char* Bl = smem + 24576;
  const int tid = threadIdx.x, wid = tid >> 6, lane = tid & 63;
  const int wr = wid >> 1, wc = wid & 1;
  const bool isG0 = blockIdx.y < 24;
  const u16* Bsrc = isG0 ? wih_hi : W1s;
  const int row0 = blockIdx.x * 64;
  const int col0 = (isG0 ? blockIdx.y : blockIdx.y - 24) * 64;

  f32x4 acc[2][2] = {};
  for (int kt = 0; kt < 8; ++kt) {
    #pragma unroll
    for (int it = 0; it < 2; ++it) {
      int s = it * 256 + tid, pr = s >> 3, pc = s & 7;
      int lch = pc ^ (pr & 7);
      size_t aoff = (size_t)(row0 + pr) * D + kt * 64 + lch * 8;
      size_t boff = (size_t)(col0 + pr) * D + kt * 64 + lch * 8;
      gload_lds16(sem_hi + aoff, Ah + it * 4096 + wid * 1024);
      gload_lds16(Bsrc + boff,   Bh + it * 4096 + wid * 1024);
      if (isG0) {
        gload_lds16(sem_lo + aoff, Al + it * 4096 + wid * 1024);
        gload_lds16(wih_lo + boff, Bl + it * 4096 + wid * 1024);
      }
    }
    asm volatile("s_waitcnt vmcnt(0)" ::: "memory");
    __syncthreads();

    const int lc = lane & 15, hi2 = lane >> 4;
    #pragma unroll
    for (int kk = 0; kk < 2; ++kk) {
      int ch = kk * 4 + hi2;
      bf16x8 afh[2], afl[2], bfh[2], bfl[2];
      #pragma unroll
      for (int mi = 0; mi < 2; ++mi) {
        int r = wr * 32 + mi * 16 + lc;
        int o = r * 128 + ((ch ^ (r & 7)) << 4);
        afh[mi] = *(const bf16x8*)(Ah + o);
        if (isG0) afl[mi] = *(const bf16x8*)(Al + o);
      }
      #pragma unroll
      for (int ci = 0; ci < 2; ++ci) {
        int r = wc * 32 + ci * 16 + lc;
        int o = r * 128 + ((ch ^ (r & 7)) << 4);
        bfh[ci] = *(const bf16x8*)(Bh + o);
        if (isG0) bfl[ci] = *(const bf16x8*)(Bl + o);
      }
      #pragma unroll
      for (int mi = 0; mi < 2; ++mi)
        #pragma unroll
        for (int ci = 0; ci < 2; ++ci) {
          f32x4 a = acc[mi][ci];
          a = mfma16(afh[mi], bfh[ci], a);
          if (isG0) {
            a = mfma16(afl[mi], bfh[ci], a);
            a = mfma16(afh[mi], bfl[ci], a);
          }
          acc[mi][ci] = a;
        }
    }
    __syncthreads();
  }
  const int lj = lane >> 4, lc2 = lane & 15;
  #pragma unroll
  for (int mi = 0; mi < 2; ++mi)
    #pragma unroll
    for (int ci = 0; ci < 2; ++ci)
      #pragma unroll
      for (int j = 0; j < 4; ++j) {
        int row = row0 + wr * 32 + mi * 16 + lj * 4 + j;
        int col = col0 + wc * 32 + ci * 16 + lc2;
        float v = acc[mi][ci][j];
        if (isG0) G0[(size_t)row * D3 + col] = v + b_ih[col];
        else      Psem[(size_t)row * D + col] = v;
      }
}

// ---------------------------------------------------------------------------
// Fused step dispatch: 1152 blocks, 4 concurrent ranges.
//   [0,512):    gates(t)   (t<32)  64r x 32c x 3g; BK=32 dbuf, T3-min sched
//   [512,768):  hidGEMM(t-2)        64x64, A=hb hi only, B=W1g, dbuf
//   [768,1024): sem(t-3)            64x64 plain, dbuf
//   [1024,1152):stats(t-1)+dyn      16 rows/block, fp32 h, two-pass
// ---------------------------------------------------------------------------
__global__ __launch_bounds__(256, 4) void fused_kernel(
    int t,
    // gates
    const u16* __restrict__ hbh_in, const u16* __restrict__ hbl_in,
    u16* __restrict__ hbh_out, u16* __restrict__ hbl_out,
    const float* __restrict__ hf_in, float* __restrict__ hf_out,
    const u16* __restrict__ whh_hi, const u16* __restrict__ whh_lo,
    const float* __restrict__ G0, const float* __restrict__ Tg,
    const float* __restrict__ bhh,
    // stats(t-1): reads hf_in (slot t-1)
    float4* __restrict__ stats_w, float* __restrict__ dyn,
    const float* __restrict__ ln_g, const float* __restrict__ ln_b,
    const float* __restrict__ Ssem, const float* __restrict__ Ssem2,
    // hidGEMM(t-2)
    const u16* __restrict__ lbh,
    const float4* __restrict__ stats_r, const u16* __restrict__ W1g,
    const float* __restrict__ Psem, const float* __restrict__ d1,
    const float* __restrict__ d2, const float* __restrict__ c1,
    const float* __restrict__ c2p, u16* __restrict__ hid_w,
    // sem(t-3)
    const u16* __restrict__ hid_r, const u16* __restrict__ w2bf,
    const float* __restrict__ zsem, const float* __restrict__ b2,
    float* __restrict__ sems)
{
  __shared__ __align__(16) char smem[32768];
  const int bid = blockIdx.x;
  const int tid = threadIdx.x, wid = tid >> 6, lane = tid & 63;
  const int wr = wid >> 1, wc = wid & 1;
  const int lc = lane & 15, hi2 = lane >> 4;
  const int lj = lane >> 4, lc2 = lane & 15;

  if (bid < 512) {
    // ----------------- gates(t): BK=32 dbuf, T3-min schedule ----------------
    if (t >= H) return;
    const int row0 = (bid & 31) * 64;
    const int gc   = (bid >> 5) * 32;
    // per-buffer 16KB at smem + (buf<<14): Ah@0, Al@4096, B@8192 (128 rows:
    // 0..95 whh_hi r/z/n, 96..127 whh_lo n-strip). Layout (R14-verified):
    // 2 rows/128B line, 64B/row, 4 chunks; slot c of row r = chunk c^((r>>1)&3).
    f32x4 acc[3][2] = {};

    const int gcol = gc + wc * 16 + lc2;

    // issue-early epilogue G0 preloads (hf_in read in epilogue; L2-hot)
    float pre_gr[2][4], pre_gz[2][4], pre_gn[2][4];
    #pragma unroll
    for (int mi = 0; mi < 2; ++mi)
      #pragma unroll
      for (int j = 0; j < 4; ++j) {
        int row = row0 + wr * 32 + mi * 16 + lj * 4 + j;
        size_t g0i = (size_t)row * D3 + gcol;
        pre_gr[mi][j] = G0[g0i];
        pre_gz[mi][j] = G0[g0i + 512];
        pre_gn[mi][j] = G0[g0i + 1024];
      }

    auto stage = [&](int b, int kt){
      char* base = smem + (b << 14);
      { int row = tid >> 2;
        int ko = kt * 32 + (((tid & 3) ^ ((tid >> 3) & 3)) << 3);
        size_t off = (size_t)(row0 + row) * D + ko;
        gload_lds16(hbh_in + off, base + wid * 1024);
        gload_lds16(hbl_in + off, base + 4096 + wid * 1024);
      }
      #pragma unroll
      for (int it = 0; it < 2; ++it) {
        int s = it * 256 + tid;
        int row = s >> 2;
        int ko = kt * 32 + (((s & 3) ^ ((s >> 3) & 3)) << 3);
        const u16* src = (row < 96)
            ? whh_hi + (size_t)((row >> 5) * D + gc + (row & 31)) * D + ko
            : whh_lo + (size_t)(2 * D + gc + (row & 31)) * D + ko;
        gload_lds16(src, base + 8192 + it * 4096 + wid * 1024);
      }
    };

    auto compute = [&](int b){
      const char* base = smem + (b << 14);
      const int ch = hi2;            // 0..3 (K=32 -> 4 chunks of 8)
      bf16x8 afh[2], afl[2];
      #pragma unroll
      for (int mi = 0; mi < 2; ++mi) {
        int ra = wr * 32 + mi * 16 + lc;
        int ao = (ra >> 1) * 128 + (ra & 1) * 64
               + ((ch ^ ((ra >> 1) & 3)) << 4);
        afh[mi] = *(const bf16x8*)(base + ao);
        afl[mi] = *(const bf16x8*)(base + 4096 + ao);
      }
      const int rloc = wc * 16 + lc;
      #pragma unroll
      for (int g = 0; g < 3; ++g) {
        int rb = g * 32 + rloc;
        int bo = (rb >> 1) * 128 + (rb & 1) * 64
               + ((ch ^ ((rb >> 1) & 3)) << 4);
        bf16x8 bh = *(const bf16x8*)(base + 8192 + bo);
        #pragma unroll
        for (int mi = 0; mi < 2; ++mi)
          acc[g][mi] = mfma16(afh[mi], bh, acc[g][mi]);
        if (g == 2)   // n-gate A-lo correction (r/z: dropped, sigmoid-damped)
          #pragma unroll
          for (int mi = 0; mi < 2; ++mi)
            acc[2][mi] = mfma16(afl[mi], bh, acc[2][mi]);
      }
      { int rb = 96 + rloc;          // n-gate weight-lo strip
        int bo = (rb >> 1) * 128 + (rb & 1) * 64
               + ((ch ^ ((rb >> 1) & 3)) << 4);
        bf16x8 bl = *(const bf16x8*)(base + 8192 + bo);
        #pragma unroll
        for (int mi = 0; mi < 2; ++mi)
          acc[2][mi] = mfma16(afh[mi], bl, acc[2][mi]);
      }
    };

    // T3-min: stage next tile into idle buffer, compute current, 1 barrier.
    stage(0, 0);
    __syncthreads();
    int buf = 0;
    for (int kt = 0; kt < 16; ++kt) {
      if (kt < 15) stage(buf ^ 1, kt + 1);
      compute(buf);
      __syncthreads();
      buf ^= 1;
    }

    const float br = bhh[gcol];
    const float bz = bhh[512 + gcol];
    const float bn = bhh[1024 + gcol];
    const float tr = Tg[t * D3 + gcol];
    const float tz = Tg[t * D3 + 512 + gcol];
    const float tn = Tg[t * D3 + 1024 + gcol];
    #pragma unroll
    for (int mi = 0; mi < 2; ++mi)
      #pragma unroll
      for (int j = 0; j < 4; ++j) {
        int row = row0 + wr * 32 + mi * 16 + lj * 4 + j;
        float gr = pre_gr[mi][j] + tr + acc[0][mi][j];
        float gz = pre_gz[mi][j] + tz + acc[1][mi][j];
        float gn = pre_gn[mi][j] + tn;                 // inn only
        float r = fsigm(gr + br);
        float z = fsigm(gz + bz);
        float n = ftanh(gn + r * (acc[2][mi][j] + bn));
        size_t hi_ = (size_t)row * D + gcol;
        float hnew = (1.f - z) * n + z * hf_in[hi_];
        hf_out[hi_] = hnew;
        u16 hh = f2bf(hnew);
        hbh_out[hi_] = hh;
        hbl_out[hi_] = f2bf(hnew - bf2f(hh));
      }
  } else if (bid < 768) {
    // ----------------- hidGEMM(t-2): 64 x 64, A = hb hi only, dbuf ---------
    if (t < 2 || t > H + 1) return;
    const int i = bid - 512;
    const int row0 = (i & 31) * 64, col0 = (i >> 5) * 64;
    f32x4 acc[2][2] = {};

    // issue-early epilogue preloads
    float pre_ps[2][2][4];
    float4 pre_st[2][4];
    #pragma unroll
    for (int mi = 0; mi < 2; ++mi)
      #pragma unroll
      for (int j = 0; j < 4; ++j) {
        int row = row0 + wr * 32 + mi * 16 + lj * 4 + j;
        pre_st[mi][j] = stats_r[row];
        #pragma unroll
        for (int ci = 0; ci < 2; ++ci) {
          int col = col0 + wc * 32 + ci * 16 + lc2;
          pre_ps[mi][ci][j] = Psem[(size_t)row * D + col];
        }
      }

    auto stage = [&](int b, int kt){
      char* base = smem + (b << 14);
      #pragma unroll
      for (int it = 0; it < 2; ++it) {
        int s = it * 256 + tid, pr = s >> 3, pc = s & 7;
        int lch = pc ^ (pr & 7);
        gload_lds16(lbh + (size_t)(row0 + pr) * D + kt * 64 + lch * 8,
                    base + it * 4096 + wid * 1024);
        gload_lds16(W1g + (size_t)(col0 + pr) * D + kt * 64 + lch * 8,
                    base + 8192 + it * 4096 + wid * 1024);
      }
    };

    stage(0, 0);
    __syncthreads();
    int buf = 0;
    for (int kt = 0; kt < 8; ++kt) {
      if (kt < 7) stage(buf ^ 1, kt + 1);
      const char* Ah = smem + (buf << 14);
      const char* Bs = Ah + 8192;
      #pragma unroll
      for (int kk = 0; kk < 2; ++kk) {
        int ch = kk * 4 + hi2;
        bf16x8 afh[2], bf[2];
        #pragma unroll
        for (int mi = 0; mi < 2; ++mi) {
          int r = wr * 32 + mi * 16 + lc;
          afh[mi] = *(const bf16x8*)(Ah + r * 128 + ((ch ^ (r & 7)) << 4));
        }
        #pragma unroll
        for (int ci = 0; ci < 2; ++ci) {
          int r = wc * 32 + ci * 16 + lc;
          bf[ci] = *(const bf16x8*)(Bs + r * 128 + ((ch ^ (r & 7)) << 4));
        }
        #pragma unroll
        for (int mi = 0; mi < 2; ++mi)
          #pragma unroll
          for (int ci = 0; ci < 2; ++ci)
            acc[mi][ci] = mfma16(afh[mi], bf[ci], acc[mi][ci]);
      }
      __syncthreads();
      buf ^= 1;
    }

    #pragma unroll
    for (int mi = 0; mi < 2; ++mi)
      #pragma unroll
      for (int ci = 0; ci < 2; ++ci)
        #pragma unroll
        for (int j = 0; j < 4; ++j) {
          int row = row0 + wr * 32 + mi * 16 + lj * 4 + j;
          int col = col0 + wc * 32 + ci * 16 + lc2;
          float4 st = pre_st[mi][j];   // {rsd1, m1*rsd1, rs2, m2*rs2}
          float hn_w1 = st.x * acc[mi][ci][j] - st.y * d1[col] + d2[col];
          float pre = st.z * (pre_ps[mi][ci][j] + hn_w1)
                      - st.w * c1[col] + c2p[col];
          float gl = 0.5f * pre * (1.f + erff(pre * 0.70710678118654752f));
          hid_w[(size_t)row * D + col] = f2bf(gl);
        }
  } else if (bid < 1024) {
    // ----------------- sem(t-3): 64 x 64 plain, dbuf -----------------------
    if (t < 3) return;
    const int ts = t - 3;
    const int i = bid - 768;
    const int row0 = (i & 31) * 64, col0 = (i >> 5) * 64;
    f32x4 acc[2][2] = {};

    // issue-early epilogue preloads
    float pre_zs[2][2][4];
    #pragma unroll
    for (int mi = 0; mi < 2; ++mi)
      #pragma unroll
      for (int ci = 0; ci < 2; ++ci)
        #pragma unroll
        for (int j = 0; j < 4; ++j) {
          int row = row0 + wr * 32 + mi * 16 + lj * 4 + j;
          int col = col0 + wc * 32 + ci * 16 + lc2;
          pre_zs[mi][ci][j] = zsem[(size_t)row * D + col];
        }

    auto stage = [&](int b, int kt){
      char* base = smem + (b << 14);
      #pragma unroll
      for (int it = 0; it < 2; ++it) {
        int s = it * 256 + tid, pr = s >> 3, pc = s & 7;
        int lch = pc ^ (pr & 7);
        gload_lds16(hid_r + (size_t)(row0 + pr) * D + kt * 64 + lch * 8,
                    base + it * 4096 + wid * 1024);
        gload_lds16(w2bf + (size_t)(col0 + pr) * D + kt * 64 + lch * 8,
                    base + 8192 + it * 4096 + wid * 1024);
      }
    };

    stage(0, 0);
    __syncthreads();
    int buf = 0;
    for (int kt = 0; kt < 8; ++kt) {
      if (kt < 7) stage(buf ^ 1, kt + 1);
      const char* As = smem + (buf << 14);
      const char* Bs = As + 8192;
      #pragma unroll
      for (int kk = 0; kk < 2; ++kk) {
        int ch = kk * 4 + hi2;
        bf16x8 af[2], bf[2];
        #pragma unroll
        for (int mi = 0; mi < 2; ++mi) {
          int r = wr * 32 + mi * 16 + lc;
          af[mi] = *(const bf16x8*)(As + r * 128 + ((ch ^ (r & 7)) << 4));
        }
        #pragma unroll
        for (int ci = 0; ci < 2; ++ci) {
          int r = wc * 32 + ci * 16 + lc;
          bf[ci] = *(const bf16x8*)(Bs + r * 128 + ((ch ^ (r & 7)) << 4));
        }
        #pragma unroll
        for (int mi = 0; mi < 2; ++mi)
          #pragma unroll
          for (int ci = 0; ci < 2; ++ci)
            acc[mi][ci] = mfma16(af[mi], bf[ci], acc[mi][ci]);
      }
      __syncthreads();
      buf ^= 1;
    }

    #pragma unroll
    for (int mi = 0; mi < 2; ++mi)
      #pragma unroll
      for (int ci = 0; ci < 2; ++ci)
        #pragma unroll
        for (int j = 0; j < 4; ++j) {
          int row = row0 + wr * 32 + mi * 16 + lj * 4 + j;
          int col = col0 + wc * 32 + ci * 16 + lc2;
          float v = pre_zs[mi][ci][j] + acc[mi][ci][j] + b2[col];
          __builtin_nontemporal_store(
              v, &sems[((size_t)row * H + ts) * D + col]);
        }
  } else {
    // ----------------- stats(t-1) + dyn(t-1): 16 rows/block, fp32 h --------
    if (t < 1 || t > H) return;
    const int tt = t - 1;
    const int base = (bid - 1024) * 16 + wid * 4;
    const float4 g0 = *(const float4*)(ln_g + lane * 8);
    const float4 g1 = *(const float4*)(ln_g + lane * 8 + 4);
    const float4 b0 = *(const float4*)(ln_b + lane * 8);
    const float4 b1v = *(const float4*)(ln_b + lane * 8 + 4);
    const float gg[8] = {g0.x,g0.y,g0.z,g0.w,g1.x,g1.y,g1.z,g1.w};
    const float bb[8] = {b0.x,b0.y,b0.z,b0.w,b1v.x,b1v.y,b1v.z,b1v.w};

    for (int rr = 0; rr < 4; ++rr) {
      const int row = base + rr;
      const float* hp = hf_in + (size_t)row * D + lane * 8;
      float4 a0 = *(const float4*)hp, a1 = *(const float4*)(hp + 4);
      float h[8] = {a0.x, a0.y, a0.z, a0.w, a1.x, a1.y, a1.z, a1.w};
      float s1 = 0.f;
      #pragma unroll
      for (int k = 0; k < 8; ++k) s1 += h[k];
      #pragma unroll
      for (int o = 1; o < 64; o <<= 1) s1 += __shfl_xor(s1, o);
      float m1 = s1 * (1.f / 512.f);
      float s2 = 0.f;
      #pragma unroll
      for (int k = 0; k < 8; ++k) {
        float dv = h[k] - m1;
        s2 += dv * dv;
      }
      #pragma unroll
      for (int o = 1; o < 64; o <<= 1) s2 += __shfl_xor(s2, o);
      float rsd1 = rsqrtf(s2 * (1.f / 512.f) + 1e-5f);

      float hn[8];
      float sh = 0.f, sh2 = 0.f;
      #pragma unroll
      for (int k = 0; k < 8; ++k) {
        float x = (h[k] - m1) * rsd1 * gg[k] + bb[k];
        hn[k] = x; sh += x; sh2 += x * x;
      }
      float* dp = dyn + ((size_t)row * H + tt) * D + lane * 8;
      f32x4 v0 = {hn[0], hn[1], hn[2], hn[3]};
      f32x4 v1 = {hn[4], hn[5], hn[6], hn[7]};
      __builtin_nontemporal_store(v0, (f32x4*)dp);
      __builtin_nontemporal_store(v1, (f32x4*)(dp + 4));

      #pragma unroll
      for (int o = 1; o < 64; o <<= 1) {
        sh += __shfl_xor(sh, o); sh2 += __shfl_xor(sh2, o);
      }
      if (lane == 0) {
        float m2 = (Ssem[row] + sh) * (1.f / 1024.f);
        float vv = (Ssem2[row] + sh2) * (1.f / 1024.f) - m2 * m2;
        float rs2 = rsqrtf(vv + 1e-5f);
        stats_w[row] = make_float4(rsd1, m1 * rsd1, rs2, m2 * rs2);
      }
    }
  }
}

// ---------------------------------------------------------------------------
extern "C" void kernel_launch(void* const* d_in, const int* in_sizes, int n_in,
                              void* d_out, int out_size, void* d_ws, size_t ws_size,
                              hipStream_t stream)
{
  (void)in_sizes; (void)n_in; (void)out_size; (void)ws_size;
  const float* z_dyn = (const float*)d_in[0];
  const float* z_sem = (const float*)d_in[1];
  const float* te_w  = (const float*)d_in[2];
  const float* w_ih  = (const float*)d_in[3];
  const float* w_hh  = (const float*)d_in[4];
  const float* b_ih  = (const float*)d_in[5];
  const float* b_hh  = (const float*)d_in[6];
  const float* ln_g  = (const float*)d_in[7];
  const float* ln_b  = (const float*)d_in[8];
  const float* ln2_g = (const float*)d_in[9];
  const float* ln2_b = (const float*)d_in[10];
  const float* w1    = (const float*)d_in[11];
  const float* b1    = (const float*)d_in[12];
  const float* w2    = (const float*)d_in[13];
  const float* b2    = (const float*)d_in[14];

  char* ws = (char*)d_ws;
  const size_t MB = 1ull << 20;
  u16* hbh[3] = { (u16*)(ws + 0),      (u16*)(ws + 2 * MB),  (u16*)(ws + 4 * MB) };
  u16* hbl[3] = { (u16*)(ws + 6 * MB), (u16*)(ws + 8 * MB),  (u16*)(ws + 10 * MB) };
  float* G0     = (float*)(ws + 12 * MB);            // 12 MB
  float* Psem   = (float*)(ws + 25 * MB);            // 4 MB
  u16*  sem_hi  = (u16*)(ws + 29 * MB);              // 2 MB
  u16*  sem_lo  = (u16*)(ws + 31 * MB);              // 2 MB
  u16*  hid0    = (u16*)(ws + 33 * MB);              // 2 MB
  u16*  hid1    = (u16*)(ws + 35 * MB);              // 2 MB
  u16*  wih_hi  = (u16*)(ws + 37 * MB);              // 1.5 MB
  u16*  wih_lo  = (u16*)(ws + 37 * MB + 1572864);    // 1.5 MB
  u16*  whh_hi  = (u16*)(ws + 40 * MB);              // 1.5 MB
  u16*  whh_lo  = (u16*)(ws + 40 * MB + 1572864);    // 1.5 MB
  u16*  W1s     = (u16*)(ws + 43 * MB);              // 512 KB
  u16*  W1g     = (u16*)(ws + 43 * MB + 524288);     // 512 KB
  u16*  w2bf    = (u16*)(ws + 44 * MB);              // 512 KB
  float* c1     = (float*)(ws + 45 * MB);
  float* c2p    = (float*)(ws + 45 * MB + 16384);
  float* d1     = (float*)(ws + 45 * MB + 32768);
  float* d2     = (float*)(ws + 45 * MB + 49152);
  float* Ssem   = (float*)(ws + 45 * MB + 65536);
  float* Ssem2  = (float*)(ws + 45 * MB + 81920);
  float4* stats0 = (float4*)(ws + 46 * MB);          // 32 KB
  float4* stats1 = (float4*)(ws + 46 * MB + 32768);  // 32 KB
  float* Tg     = (float*)(ws + 47 * MB);            // 192 KB
  float* hf0    = (float*)(ws + 48 * MB);            // 4 MB
  float* hf1    = (float*)(ws + 52 * MB);            // 4 MB

  float* outp = (float*)d_out;
  float* out_dyn  = outp;
  float* out_sems = outp + OUT_HALF;

  // initial state h(-1): hb slot 2 (== (-1) mod 3), hf slot 1 (== (-1) & 1)
  prep_kernel<<<4096, 256, 0, stream>>>(
      z_dyn, z_sem, te_w, w_ih, w_hh, ln_g, ln_b, ln2_g, ln2_b, w1, b1, w2,
      hf1, hbh[2], hbl[2], sem_hi, sem_lo, wih_hi, wih_lo, whh_hi, whh_lo,
      W1s, W1g, w2bf, c1, c2p, d1, d2, Tg);
  rowstats_kernel<<<512, 256, 0, stream>>>(z_sem, Ssem, Ssem2);
  setup_kernel<<<dim3(32, 32), 256, 0, stream>>>(
      sem_hi, sem_lo, wih_hi, wih_lo, W1s, G0, Psem, b_ih);

  for (int t = 0; t <= H + 2; ++t) {
    int s_out  = ((t % 3) + 3) % 3;          // gates write hb slot(t)
    int s_in   = (((t - 1) % 3) + 3) % 3;    // gates read hb slot(t-1)
    int s_ln   = (((t - 2) % 3) + 3) % 3;    // hidGEMM reads hb slot(t-2)
    float* hf_out      = (t & 1) ? hf1 : hf0;
    const float* hf_in = (t & 1) ? hf0 : hf1;   // slot (t-1)&1
    float4* st_w = ((t - 1) & 1) ? stats1 : stats0;
    const float4* st_r = ((t - 2) & 1) ? stats1 : stats0;
    u16* hidw = ((t - 2) & 1) ? hid1 : hid0;
    const u16* hidr = ((t - 3) & 1) ? hid1 : hid0;

    fused_kernel<<<dim3(1152), dim3(256), 0, stream>>>(
        t,
        hbh[s_in], hbl[s_in], hbh[s_out], hbl[s_out],
        hf_in, hf_out,
        whh_hi, whh_lo, G0, Tg, b_hh,
        st_w, out_dyn, ln_g, ln_b, Ssem, Ssem2,
        hbh[s_ln], st_r, W1g, Psem, d1, d2, c1, c2p, hidw,
        hidr, w2bf, z_sem, b2, out_sems);
  }
}

// Round 17
// 706.157 us; speedup vs baseline: 1.1045x; 1.1045x over previous
//
#include <hip/hip_runtime.h>
#include <math.h>

// ---------------------------------------------------------------------------
// TemporalUnitRolloutV341 — GRU rollout, 32 steps over 2048 rows of D=512.
// R17 = R12 (best: 722us) + two proven-safe deltas backported:
//   (a) gates r/z drop the A-lo MFMA term (28->20 MFMA/kt; R16 proved
//       absmax bit-identical 0.03125 — sigmoid-damped)
//   (b) Tg (tr/tz/tn) loads hoisted above the K-loop (T14 issue-early)
// R13-R16 falsified the BK=32 gates rebuild 3x (769/780 vs 722): at small
// tiles, fewer/fatter phases beat staging-drain elimination. R12 structure
// retained verbatim.
// ---------------------------------------------------------------------------

typedef unsigned short u16;
using bf16x8 = __attribute__((ext_vector_type(8))) short;
using f32x4  = __attribute__((ext_vector_type(4))) float;

#define DEV __device__ __forceinline__

constexpr int D   = 512;
constexpr int D3  = 1536;
constexpr int H   = 32;
constexpr int BU  = 2048;
constexpr long long OUT_HALF = (long long)BU * H * D;

DEV u16 f2bf(float x){
  union { float f; unsigned u; } c; c.f = x;
  unsigned u = c.u;
  u += 0x7fffu + ((u >> 16) & 1u);
  return (u16)(u >> 16);
}
DEV float bf2f(u16 b){
  union { unsigned u; float f; } c; c.u = ((unsigned)b) << 16; return c.f;
}

DEV void gload_lds16(const void* g, void* l){
  __builtin_amdgcn_global_load_lds(
      (const __attribute__((address_space(1))) void*)g,
      (__attribute__((address_space(3))) void*)l, 16, 0, 0);
}

DEV f32x4 mfma16(bf16x8 a, bf16x8 b, f32x4 c){
  return __builtin_amdgcn_mfma_f32_16x16x32_bf16(a, b, c, 0, 0, 0);
}

DEV float fsigm(float x){ return 1.f / (1.f + __expf(-x)); }
DEV float ftanh(float x){ return 1.f - 2.f / (1.f + __expf(2.f * x)); }

// ---------------------------------------------------------------------------
// prep: hi/lo splits, W1s, W1g, c1/c2p/d1/d2, Tg, initial state.
// ---------------------------------------------------------------------------
__global__ __launch_bounds__(256) void prep_kernel(
    const float* __restrict__ z_dyn, const float* __restrict__ z_sem,
    const float* __restrict__ te_w,  const float* __restrict__ w_ih,
    const float* __restrict__ w_hh,  const float* __restrict__ ln_g,
    const float* __restrict__ ln_b,  const float* __restrict__ ln2_g,
    const float* __restrict__ ln2_b, const float* __restrict__ w1,
    const float* __restrict__ b1,    const float* __restrict__ w2,
    float* __restrict__ h1, u16* __restrict__ hbh2, u16* __restrict__ hbl2,
    u16* __restrict__ sem_hi, u16* __restrict__ sem_lo,
    u16* __restrict__ wih_hi, u16* __restrict__ wih_lo,
    u16* __restrict__ whh_hi, u16* __restrict__ whh_lo,
    u16* __restrict__ W1s, u16* __restrict__ W1g, u16* __restrict__ w2bf,
    float* __restrict__ c1, float* __restrict__ c2p,
    float* __restrict__ d1, float* __restrict__ d2, float* __restrict__ Tg)
{
  int i = blockIdx.x * 256 + threadIdx.x;
  if (i < BU * D) {
    float hv = z_dyn[i];
    h1[i] = hv;
    u16 hh = f2bf(hv);
    hbh2[i] = hh;
    hbl2[i] = f2bf(hv - bf2f(hh));
    float sv = z_sem[i];
    u16 sh_ = f2bf(sv);
    sem_hi[i] = sh_;
    sem_lo[i] = f2bf(sv - bf2f(sh_));
  }
  if (i < D3 * D) {
    float wv = w_ih[i];
    u16 wh = f2bf(wv);
    wih_hi[i] = wh;
    wih_lo[i] = f2bf(wv - bf2f(wh));
    float uv = w_hh[i];
    u16 uh = f2bf(uv);
    whh_hi[i] = uh;
    whh_lo[i] = f2bf(uv - bf2f(uh));
  }
  if (i < D * D) {
    int k = i >> 9, j = i & 511;
    W1s[i]  = f2bf(w1[k * 1024 + j] * ln2_g[j]);
    w2bf[i] = f2bf(w2[i]);
  }
  if (i < D * 64) {
    // one wave per output row r: coalesced w1 reads, shfl reduce
    int r = i >> 6, ln = i & 63;
    float sc1 = 0.f, sc2 = 0.f, sd1 = 0.f, sd2 = 0.f;
    #pragma unroll
    for (int jj = 0; jj < 8; ++jj) {
      int j = jj * 64 + ln;
      float wA = w1[r * 1024 + j];
      float wB = w1[r * 1024 + 512 + j];
      sc1 += wA * ln2_g[j] + wB * ln2_g[512 + j];
      sc2 += wA * ln2_b[j] + wB * ln2_b[512 + j];
      float wBg = wB * ln2_g[512 + j];          // = W1h[r][j]
      float wg = wBg * ln_g[j];                 // = W1g[r][j]
      sd1 += wg;
      sd2 += wBg * ln_b[j];
      W1g[r * 512 + j] = f2bf(wg);
    }
    #pragma unroll
    for (int o = 1; o < 64; o <<= 1) {
      sc1 += __shfl_xor(sc1, o); sc2 += __shfl_xor(sc2, o);
      sd1 += __shfl_xor(sd1, o); sd2 += __shfl_xor(sd2, o);
    }
    if (ln == 0) {
      c1[r] = sc1;
      c2p[r] = sc2 + b1[r];
      d1[r] = sd1;
      d2[r] = sd2;
    }
  }
  if (i < H * D3) {
    // broadcast-friendly: 32 lanes share one w_ih row (uniform load)
    int c = i >> 5, t = i & 31;
    float s = 0.f;
    for (int d0 = 0; d0 < D; ++d0) s += te_w[t * D + d0] * w_ih[c * D + d0];
    Tg[t * D3 + c] = s;
  }
}

// Per-row sums of sem and sem^2 (ln2 stats split). One wave per row.
__global__ __launch_bounds__(256) void rowstats_kernel(
    const float* __restrict__ sem, float* __restrict__ Ssem,
    float* __restrict__ Ssem2)
{
  const int wid = threadIdx.x >> 6, lane = threadIdx.x & 63;
  const int row = blockIdx.x * 4 + wid;
  const float* p = sem + (size_t)row * D + lane * 8;
  float4 a0 = *(const float4*)p;
  float4 a1 = *(const float4*)(p + 4);
  float s  = a0.x + a0.y + a0.z + a0.w + a1.x + a1.y + a1.z + a1.w;
  float s2 = a0.x*a0.x + a0.y*a0.y + a0.z*a0.z + a0.w*a0.w
           + a1.x*a1.x + a1.y*a1.y + a1.z*a1.z + a1.w*a1.w;
  #pragma unroll
  for (int o = 1; o < 64; o <<= 1) { s += __shfl_xor(s, o); s2 += __shfl_xor(s2, o); }
  if (lane == 0) { Ssem[row] = s; Ssem2[row] = s2; }
}

// ---------------------------------------------------------------------------
// Setup GEMMs: grid (32, 32). by<24 -> G0 tile (bf16x3, +b_ih);
// by>=24 -> Psem tile (plain bf16). 64x64 NT, single-buffered 32KB LDS.
// ---------------------------------------------------------------------------
__global__ __launch_bounds__(256) void setup_kernel(
    const u16* __restrict__ sem_hi, const u16* __restrict__ sem_lo,
    const u16* __restrict__ wih_hi, const u16* __restrict__ wih_lo,
    const u16* __restrict__ W1s, float* __restrict__ G0,
    float* __restrict__ Psem, const float* __restrict__ b_ih)
{
  __shared__ __align__(16) char smem[32768];
  char* Ah = smem;
  char* Al = smem + 8192;
  char* Bh = smem + 16384;
  char* Bl = smem + 24576;
  const int tid = threadIdx.x, wid = tid >> 6, lane = tid & 63;
  const int wr = wid >> 1, wc = wid & 1;
  const bool isG0 = blockIdx.y < 24;
  const u16* Bsrc = isG0 ? wih_hi : W1s;
  const int row0 = blockIdx.x * 64;
  const int col0 = (isG0 ? blockIdx.y : blockIdx.y - 24) * 64;

  f32x4 acc[2][2] = {};
  for (int kt = 0; kt < 8; ++kt) {
    #pragma unroll
    for (int it = 0; it < 2; ++it) {
      int s = it * 256 + tid, pr = s >> 3, pc = s & 7;
      int lch = pc ^ (pr & 7);
      size_t aoff = (size_t)(row0 + pr) * D + kt * 64 + lch * 8;
      size_t boff = (size_t)(col0 + pr) * D + kt * 64 + lch * 8;
      gload_lds16(sem_hi + aoff, Ah + it * 4096 + wid * 1024);
      gload_lds16(Bsrc + boff,   Bh + it * 4096 + wid * 1024);
      if (isG0) {
        gload_lds16(sem_lo + aoff, Al + it * 4096 + wid * 1024);
        gload_lds16(wih_lo + boff, Bl + it * 4096 + wid * 1024);
      }
    }
    asm volatile("s_waitcnt vmcnt(0)" ::: "memory");
    __syncthreads();

    const int lc = lane & 15, hi2 = lane >> 4;
    #pragma unroll
    for (int kk = 0; kk < 2; ++kk) {
      int ch = kk * 4 + hi2;
      bf16x8 afh[2], afl[2], bfh[2], bfl[2];
      #pragma unroll
      for (int mi = 0; mi < 2; ++mi) {
        int r = wr * 32 + mi * 16 + lc;
        int o = r * 128 + ((ch ^ (r & 7)) << 4);
        afh[mi] = *(const bf16x8*)(Ah + o);
        if (isG0) afl[mi] = *(const bf16x8*)(Al + o);
      }
      #pragma unroll
      for (int ci = 0; ci < 2; ++ci) {
        int r = wc * 32 + ci * 16 + lc;
        int o = r * 128 + ((ch ^ (r & 7)) << 4);
        bfh[ci] = *(const bf16x8*)(Bh + o);
        if (isG0) bfl[ci] = *(const bf16x8*)(Bl + o);
      }
      #pragma unroll
      for (int mi = 0; mi < 2; ++mi)
        #pragma unroll
        for (int ci = 0; ci < 2; ++ci) {
          f32x4 a = acc[mi][ci];
          a = mfma16(afh[mi], bfh[ci], a);
          if (isG0) {
            a = mfma16(afl[mi], bfh[ci], a);
            a = mfma16(afh[mi], bfl[ci], a);
          }
          acc[mi][ci] = a;
        }
    }
    __syncthreads();
  }
  const int lj = lane >> 4, lc2 = lane & 15;
  #pragma unroll
  for (int mi = 0; mi < 2; ++mi)
    #pragma unroll
    for (int ci = 0; ci < 2; ++ci)
      #pragma unroll
      for (int j = 0; j < 4; ++j) {
        int row = row0 + wr * 32 + mi * 16 + lj * 4 + j;
        int col = col0 + wc * 32 + ci * 16 + lc2;
        float v = acc[mi][ci][j];
        if (isG0) G0[(size_t)row * D3 + col] = v + b_ih[col];
        else      Psem[(size_t)row * D + col] = v;
      }
}

// ---------------------------------------------------------------------------
// Fused step dispatch: 1152 blocks, 4 concurrent ranges.
//   [0,512):    gates(t)      (t<32)  64r x 32c x 3g; r/z bf16x2, n bf16x3
//   [512,768):  hidGEMM(t-2)           64x64, A=hb hi only, B=W1g, dbuf
//   [768,1024): sem(t-3)               64x64 plain, dbuf
//   [1024,1152):stats(t-1)+dyn         16 rows/block, fp32 h, two-pass
// ---------------------------------------------------------------------------
__global__ __launch_bounds__(256, 4) void fused_kernel(
    int t,
    // gates
    const u16* __restrict__ hbh_in, const u16* __restrict__ hbl_in,
    u16* __restrict__ hbh_out, u16* __restrict__ hbl_out,
    const float* __restrict__ hf_in, float* __restrict__ hf_out,
    const u16* __restrict__ whh_hi, const u16* __restrict__ whh_lo,
    const float* __restrict__ G0, const float* __restrict__ Tg,
    const float* __restrict__ bhh,
    // stats(t-1): reads hf_in (slot t-1)
    float4* __restrict__ stats_w, float* __restrict__ dyn,
    const float* __restrict__ ln_g, const float* __restrict__ ln_b,
    const float* __restrict__ Ssem, const float* __restrict__ Ssem2,
    // hidGEMM(t-2)
    const u16* __restrict__ lbh,
    const float4* __restrict__ stats_r, const u16* __restrict__ W1g,
    const float* __restrict__ Psem, const float* __restrict__ d1,
    const float* __restrict__ d2, const float* __restrict__ c1,
    const float* __restrict__ c2p, u16* __restrict__ hid_w,
    // sem(t-3)
    const u16* __restrict__ hid_r, const u16* __restrict__ w2bf,
    const float* __restrict__ zsem, const float* __restrict__ b2,
    float* __restrict__ sems)
{
  __shared__ __align__(16) char smem[32768];
  const int bid = blockIdx.x;
  const int tid = threadIdx.x, wid = tid >> 6, lane = tid & 63;
  const int wr = wid >> 1, wc = wid & 1;
  const int lc = lane & 15, hi2 = lane >> 4;
  const int lj = lane >> 4, lc2 = lane & 15;

  if (bid < 512) {
    // ----------------- gates(t): 64 rows x (32 cols x 3 gates) -------------
    if (t >= H) return;
    const int row0 = (bid & 31) * 64;
    const int gc   = (bid >> 5) * 32;
    char* Ah = smem;             // 8 KB
    char* Al = smem + 8192;      // 8 KB
    char* Bh = smem + 16384;     // 12 KB (96 rows)
    char* Bl = smem + 28672;     // 4 KB  (32 rows, n-gate only)
    f32x4 acc[3][2] = {};

    const int gcol = gc + wc * 16 + lc2;

    // issue-early epilogue operand preloads: latency hides under K-loop
    const float tr = Tg[t * D3 + gcol];
    const float tz = Tg[t * D3 + 512 + gcol];
    const float tn = Tg[t * D3 + 1024 + gcol];
    float pre_gr[2][4], pre_gz[2][4], pre_gn[2][4], pre_hf[2][4];
    #pragma unroll
    for (int mi = 0; mi < 2; ++mi)
      #pragma unroll
      for (int j = 0; j < 4; ++j) {
        int row = row0 + wr * 32 + mi * 16 + lj * 4 + j;
        size_t g0i = (size_t)row * D3 + gcol;
        pre_gr[mi][j] = G0[g0i];
        pre_gz[mi][j] = G0[g0i + 512];
        pre_gn[mi][j] = G0[g0i + 1024];
        pre_hf[mi][j] = hf_in[(size_t)row * D + gcol];
      }

    for (int kt = 0; kt < 8; ++kt) {
      #pragma unroll
      for (int it = 0; it < 2; ++it) {
        int s = it * 256 + tid, pr = s >> 3, pc = s & 7;
        int lch = pc ^ (pr & 7);
        size_t off = (size_t)(row0 + pr) * D + kt * 64 + lch * 8;
        gload_lds16(hbh_in + off, Ah + it * 4096 + wid * 1024);
        gload_lds16(hbl_in + off, Al + it * 4096 + wid * 1024);
      }
      #pragma unroll
      for (int it = 0; it < 3; ++it) {
        int s = it * 256 + tid, pr = s >> 3, pc = s & 7;
        int lch = pc ^ (pr & 7);
        int g = pr >> 5, lr = pr & 31;
        gload_lds16(whh_hi + (size_t)(g * D + gc + lr) * D + kt * 64 + lch * 8,
                    Bh + it * 4096 + wid * 1024);
      }
      { // n-gate weight-lo strip
        int pr = tid >> 3, pc = tid & 7;
        int lch = pc ^ (pr & 7);
        gload_lds16(whh_lo + (size_t)(2 * D + gc + pr) * D + kt * 64 + lch * 8,
                    Bl + wid * 1024);
      }
      asm volatile("s_waitcnt vmcnt(0)" ::: "memory");
      __syncthreads();

      #pragma unroll
      for (int kk = 0; kk < 2; ++kk) {
        int ch = kk * 4 + hi2;
        bf16x8 afh[2], afl[2];
        #pragma unroll
        for (int mi = 0; mi < 2; ++mi) {
          int r = wr * 32 + mi * 16 + lc;
          int o = r * 128 + ((ch ^ (r & 7)) << 4);
          afh[mi] = *(const bf16x8*)(Ah + o);
          afl[mi] = *(const bf16x8*)(Al + o);
        }
        const int rloc = wc * 16 + lc;                 // 0..31 within a gate
        #pragma unroll
        for (int g = 0; g < 3; ++g) {
          int rb = g * 32 + rloc;
          int bo = rb * 128 + ((ch ^ (rb & 7)) << 4);
          bf16x8 bh = *(const bf16x8*)(Bh + bo);
          #pragma unroll
          for (int mi = 0; mi < 2; ++mi) {
            f32x4 a = acc[g][mi];
            a = mfma16(afh[mi], bh, a);
            if (g == 2) a = mfma16(afl[mi], bh, a);  // A-lo: n-gate only
            acc[g][mi] = a;
          }
        }
        { // n-gate extra term: hi * weight-lo
          int bo = rloc * 128 + ((ch ^ (rloc & 7)) << 4);
          bf16x8 bl = *(const bf16x8*)(Bl + bo);
          #pragma unroll
          for (int mi = 0; mi < 2; ++mi)
            acc[2][mi] = mfma16(afh[mi], bl, acc[2][mi]);
        }
      }
      __syncthreads();
    }

    const float br = bhh[gcol];
    const float bz = bhh[512 + gcol];
    const float bn = bhh[1024 + gcol];
    #pragma unroll
    for (int mi = 0; mi < 2; ++mi)
      #pragma unroll
      for (int j = 0; j < 4; ++j) {
        int row = row0 + wr * 32 + mi * 16 + lj * 4 + j;
        float gr = pre_gr[mi][j] + tr + acc[0][mi][j];
        float gz = pre_gz[mi][j] + tz + acc[1][mi][j];
        float gn = pre_gn[mi][j] + tn;                 // inn only
        float r = fsigm(gr + br);
        float z = fsigm(gz + bz);
        float n = ftanh(gn + r * (acc[2][mi][j] + bn));
        size_t hi_ = (size_t)row * D + gcol;
        float hnew = (1.f - z) * n + z * pre_hf[mi][j];
        hf_out[hi_] = hnew;
        u16 hh = f2bf(hnew);
        hbh_out[hi_] = hh;
        hbl_out[hi_] = f2bf(hnew - bf2f(hh));
      }
  } else if (bid < 768) {
    // ----------------- hidGEMM(t-2): 64 x 64, A = hb hi only, dbuf ---------
    if (t < 2 || t > H + 1) return;
    const int i = bid - 512;
    const int row0 = (i & 31) * 64, col0 = (i >> 5) * 64;
    f32x4 acc[2][2] = {};

    // issue-early epilogue preloads
    float pre_ps[2][2][4];
    float4 pre_st[2][4];
    #pragma unroll
    for (int mi = 0; mi < 2; ++mi)
      #pragma unroll
      for (int j = 0; j < 4; ++j) {
        int row = row0 + wr * 32 + mi * 16 + lj * 4 + j;
        pre_st[mi][j] = stats_r[row];
        #pragma unroll
        for (int ci = 0; ci < 2; ++ci) {
          int col = col0 + wc * 32 + ci * 16 + lc2;
          pre_ps[mi][ci][j] = Psem[(size_t)row * D + col];
        }
      }

    auto stage = [&](int b, int kt){
      char* base = smem + (b << 14);
      #pragma unroll
      for (int it = 0; it < 2; ++it) {
        int s = it * 256 + tid, pr = s >> 3, pc = s & 7;
        int lch = pc ^ (pr & 7);
        gload_lds16(lbh + (size_t)(row0 + pr) * D + kt * 64 + lch * 8,
                    base + it * 4096 + wid * 1024);
        gload_lds16(W1g + (size_t)(col0 + pr) * D + kt * 64 + lch * 8,
                    base + 8192 + it * 4096 + wid * 1024);
      }
    };

    stage(0, 0);
    __syncthreads();
    int buf = 0;
    for (int kt = 0; kt < 8; ++kt) {
      if (kt < 7) stage(buf ^ 1, kt + 1);
      const char* Ah = smem + (buf << 14);
      const char* Bs = Ah + 8192;
      #pragma unroll
      for (int kk = 0; kk < 2; ++kk) {
        int ch = kk * 4 + hi2;
        bf16x8 afh[2], bf[2];
        #pragma unroll
        for (int mi = 0; mi < 2; ++mi) {
          int r = wr * 32 + mi * 16 + lc;
          afh[mi] = *(const bf16x8*)(Ah + r * 128 + ((ch ^ (r & 7)) << 4));
        }
        #pragma unroll
        for (int ci = 0; ci < 2; ++ci) {
          int r = wc * 32 + ci * 16 + lc;
          bf[ci] = *(const bf16x8*)(Bs + r * 128 + ((ch ^ (r & 7)) << 4));
        }
        #pragma unroll
        for (int mi = 0; mi < 2; ++mi)
          #pragma unroll
          for (int ci = 0; ci < 2; ++ci)
            acc[mi][ci] = mfma16(afh[mi], bf[ci], acc[mi][ci]);
      }
      __syncthreads();
      buf ^= 1;
    }

    #pragma unroll
    for (int mi = 0; mi < 2; ++mi)
      #pragma unroll
      for (int ci = 0; ci < 2; ++ci)
        #pragma unroll
        for (int j = 0; j < 4; ++j) {
          int row = row0 + wr * 32 + mi * 16 + lj * 4 + j;
          int col = col0 + wc * 32 + ci * 16 + lc2;
          float4 st = pre_st[mi][j];   // {rsd1, m1*rsd1, rs2, m2*rs2}
          float hn_w1 = st.x * acc[mi][ci][j] - st.y * d1[col] + d2[col];
          float pre = st.z * (pre_ps[mi][ci][j] + hn_w1)
                      - st.w * c1[col] + c2p[col];
          float gl = 0.5f * pre * (1.f + erff(pre * 0.70710678118654752f));
          hid_w[(size_t)row * D + col] = f2bf(gl);
        }
  } else if (bid < 1024) {
    // ----------------- sem(t-3): 64 x 64 plain, dbuf -----------------------
    if (t < 3) return;
    const int ts = t - 3;
    const int i = bid - 768;
    const int row0 = (i & 31) * 64, col0 = (i >> 5) * 64;
    f32x4 acc[2][2] = {};

    // issue-early epilogue preloads
    float pre_zs[2][2][4];
    #pragma unroll
    for (int mi = 0; mi < 2; ++mi)
      #pragma unroll
      for (int ci = 0; ci < 2; ++ci)
        #pragma unroll
        for (int j = 0; j < 4; ++j) {
          int row = row0 + wr * 32 + mi * 16 + lj * 4 + j;
          int col = col0 + wc * 32 + ci * 16 + lc2;
          pre_zs[mi][ci][j] = zsem[(size_t)row * D + col];
        }

    auto stage = [&](int b, int kt){
      char* base = smem + (b << 14);
      #pragma unroll
      for (int it = 0; it < 2; ++it) {
        int s = it * 256 + tid, pr = s >> 3, pc = s & 7;
        int lch = pc ^ (pr & 7);
        gload_lds16(hid_r + (size_t)(row0 + pr) * D + kt * 64 + lch * 8,
                    base + it * 4096 + wid * 1024);
        gload_lds16(w2bf + (size_t)(col0 + pr) * D + kt * 64 + lch * 8,
                    base + 8192 + it * 4096 + wid * 1024);
      }
    };

    stage(0, 0);
    __syncthreads();
    int buf = 0;
    for (int kt = 0; kt < 8; ++kt) {
      if (kt < 7) stage(buf ^ 1, kt + 1);
      const char* As = smem + (buf << 14);
      const char* Bs = As + 8192;
      #pragma unroll
      for (int kk = 0; kk < 2; ++kk) {
        int ch = kk * 4 + hi2;
        bf16x8 af[2], bf[2];
        #pragma unroll
        for (int mi = 0; mi < 2; ++mi) {
          int r = wr * 32 + mi * 16 + lc;
          af[mi] = *(const bf16x8*)(As + r * 128 + ((ch ^ (r & 7)) << 4));
        }
        #pragma unroll
        for (int ci = 0; ci < 2; ++ci) {
          int r = wc * 32 + ci * 16 + lc;
          bf[ci] = *(const bf16x8*)(Bs + r * 128 + ((ch ^ (r & 7)) << 4));
        }
        #pragma unroll
        for (int mi = 0; mi < 2; ++mi)
          #pragma unroll
          for (int ci = 0; ci < 2; ++ci)
            acc[mi][ci] = mfma16(af[mi], bf[ci], acc[mi][ci]);
      }
      __syncthreads();
      buf ^= 1;
    }

    #pragma unroll
    for (int mi = 0; mi < 2; ++mi)
      #pragma unroll
      for (int ci = 0; ci < 2; ++ci)
        #pragma unroll
        for (int j = 0; j < 4; ++j) {
          int row = row0 + wr * 32 + mi * 16 + lj * 4 + j;
          int col = col0 + wc * 32 + ci * 16 + lc2;
          float v = pre_zs[mi][ci][j] + acc[mi][ci][j] + b2[col];
          __builtin_nontemporal_store(
              v, &sems[((size_t)row * H + ts) * D + col]);
        }
  } else {
    // ----------------- stats(t-1) + dyn(t-1): 16 rows/block, fp32 h --------
    if (t < 1 || t > H) return;
    const int tt = t - 1;
    const int base = (bid - 1024) * 16 + wid * 4;
    const float4 g0 = *(const float4*)(ln_g + lane * 8);
    const float4 g1 = *(const float4*)(ln_g + lane * 8 + 4);
    const float4 b0 = *(const float4*)(ln_b + lane * 8);
    const float4 b1v = *(const float4*)(ln_b + lane * 8 + 4);
    const float gg[8] = {g0.x,g0.y,g0.z,g0.w,g1.x,g1.y,g1.z,g1.w};
    const float bb[8] = {b0.x,b0.y,b0.z,b0.w,b1v.x,b1v.y,b1v.z,b1v.w};

    for (int rr = 0; rr < 4; ++rr) {
      const int row = base + rr;
      const float* hp = hf_in + (size_t)row * D + lane * 8;
      float4 a0 = *(const float4*)hp, a1 = *(const float4*)(hp + 4);
      float h[8] = {a0.x, a0.y, a0.z, a0.w, a1.x, a1.y, a1.z, a1.w};
      float s1 = 0.f;
      #pragma unroll
      for (int k = 0; k < 8; ++k) s1 += h[k];
      #pragma unroll
      for (int o = 1; o < 64; o <<= 1) s1 += __shfl_xor(s1, o);
      float m1 = s1 * (1.f / 512.f);
      float s2 = 0.f;
      #pragma unroll
      for (int k = 0; k < 8; ++k) {
        float dv = h[k] - m1;
        s2 += dv * dv;
      }
      #pragma unroll
      for (int o = 1; o < 64; o <<= 1) s2 += __shfl_xor(s2, o);
      float rsd1 = rsqrtf(s2 * (1.f / 512.f) + 1e-5f);

      float hn[8];
      float sh = 0.f, sh2 = 0.f;
      #pragma unroll
      for (int k = 0; k < 8; ++k) {
        float x = (h[k] - m1) * rsd1 * gg[k] + bb[k];
        hn[k] = x; sh += x; sh2 += x * x;
      }
      float* dp = dyn + ((size_t)row * H + tt) * D + lane * 8;
      f32x4 v0 = {hn[0], hn[1], hn[2], hn[3]};
      f32x4 v1 = {hn[4], hn[5], hn[6], hn[7]};
      __builtin_nontemporal_store(v0, (f32x4*)dp);
      __builtin_nontemporal_store(v1, (f32x4*)(dp + 4));

      #pragma unroll
      for (int o = 1; o < 64; o <<= 1) {
        sh += __shfl_xor(sh, o); sh2 += __shfl_xor(sh2, o);
      }
      if (lane == 0) {
        float m2 = (Ssem[row] + sh) * (1.f / 1024.f);
        float vv = (Ssem2[row] + sh2) * (1.f / 1024.f) - m2 * m2;
        float rs2 = rsqrtf(vv + 1e-5f);
        stats_w[row] = make_float4(rsd1, m1 * rsd1, rs2, m2 * rs2);
      }
    }
  }
}

// ---------------------------------------------------------------------------
extern "C" void kernel_launch(void* const* d_in, const int* in_sizes, int n_in,
                              void* d_out, int out_size, void* d_ws, size_t ws_size,
                              hipStream_t stream)
{
  (void)in_sizes; (void)n_in; (void)out_size; (void)ws_size;
  const float* z_dyn = (const float*)d_in[0];
  const float* z_sem = (const float*)d_in[1];
  const float* te_w  = (const float*)d_in[2];
  const float* w_ih  = (const float*)d_in[3];
  const float* w_hh  = (const float*)d_in[4];
  const float* b_ih  = (const float*)d_in[5];
  const float* b_hh  = (const float*)d_in[6];
  const float* ln_g  = (const float*)d_in[7];
  const float* ln_b  = (const float*)d_in[8];
  const float* ln2_g = (const float*)d_in[9];
  const float* ln2_b = (const float*)d_in[10];
  const float* w1    = (const float*)d_in[11];
  const float* b1    = (const float*)d_in[12];
  const float* w2    = (const float*)d_in[13];
  const float* b2    = (const float*)d_in[14];

  char* ws = (char*)d_ws;
  const size_t MB = 1ull << 20;
  u16* hbh[3] = { (u16*)(ws + 0),      (u16*)(ws + 2 * MB),  (u16*)(ws + 4 * MB) };
  u16* hbl[3] = { (u16*)(ws + 6 * MB), (u16*)(ws + 8 * MB),  (u16*)(ws + 10 * MB) };
  float* G0     = (float*)(ws + 12 * MB);            // 12 MB
  float* Psem   = (float*)(ws + 25 * MB);            // 4 MB
  u16*  sem_hi  = (u16*)(ws + 29 * MB);              // 2 MB
  u16*  sem_lo  = (u16*)(ws + 31 * MB);              // 2 MB
  u16*  hid0    = (u16*)(ws + 33 * MB);              // 2 MB
  u16*  hid1    = (u16*)(ws + 35 * MB);              // 2 MB
  u16*  wih_hi  = (u16*)(ws + 37 * MB);              // 1.5 MB
  u16*  wih_lo  = (u16*)(ws + 37 * MB + 1572864);    // 1.5 MB
  u16*  whh_hi  = (u16*)(ws + 40 * MB);              // 1.5 MB
  u16*  whh_lo  = (u16*)(ws + 40 * MB + 1572864);    // 1.5 MB
  u16*  W1s     = (u16*)(ws + 43 * MB);              // 512 KB
  u16*  W1g     = (u16*)(ws + 43 * MB + 524288);     // 512 KB
  u16*  w2bf    = (u16*)(ws + 44 * MB);              // 512 KB
  float* c1     = (float*)(ws + 45 * MB);
  float* c2p    = (float*)(ws + 45 * MB + 16384);
  float* d1     = (float*)(ws + 45 * MB + 32768);
  float* d2     = (float*)(ws + 45 * MB + 49152);
  float* Ssem   = (float*)(ws + 45 * MB + 65536);
  float* Ssem2  = (float*)(ws + 45 * MB + 81920);
  float4* stats0 = (float4*)(ws + 46 * MB);          // 32 KB
  float4* stats1 = (float4*)(ws + 46 * MB + 32768);  // 32 KB
  float* Tg     = (float*)(ws + 47 * MB);            // 192 KB
  float* hf0    = (float*)(ws + 48 * MB);            // 4 MB
  float* hf1    = (float*)(ws + 52 * MB);            // 4 MB

  float* outp = (float*)d_out;
  float* out_dyn  = outp;
  float* out_sems = outp + OUT_HALF;

  // initial state h(-1): hb slot 2 (== (-1) mod 3), hf slot 1 (== (-1) & 1)
  prep_kernel<<<4096, 256, 0, stream>>>(
      z_dyn, z_sem, te_w, w_ih, w_hh, ln_g, ln_b, ln2_g, ln2_b, w1, b1, w2,
      hf1, hbh[2], hbl[2], sem_hi, sem_lo, wih_hi, wih_lo, whh_hi, whh_lo,
      W1s, W1g, w2bf, c1, c2p, d1, d2, Tg);
  rowstats_kernel<<<512, 256, 0, stream>>>(z_sem, Ssem, Ssem2);
  setup_kernel<<<dim3(32, 32), 256, 0, stream>>>(
      sem_hi, sem_lo, wih_hi, wih_lo, W1s, G0, Psem, b_ih);

  for (int t = 0; t <= H + 2; ++t) {
    int s_out  = ((t % 3) + 3) % 3;          // gates write hb slot(t)
    int s_in   = (((t - 1) % 3) + 3) % 3;    // gates read hb slot(t-1)
    int s_ln   = (((t - 2) % 3) + 3) % 3;    // hidGEMM reads hb slot(t-2)
    float* hf_out      = (t & 1) ? hf1 : hf0;
    const float* hf_in = (t & 1) ? hf0 : hf1;   // slot (t-1)&1
    float4* st_w = ((t - 1) & 1) ? stats1 : stats0;
    const float4* st_r = ((t - 2) & 1) ? stats1 : stats0;
    u16* hidw = ((t - 2) & 1) ? hid1 : hid0;
    const u16* hidr = ((t - 3) & 1) ? hid1 : hid0;

    fused_kernel<<<dim3(1152), dim3(256), 0, stream>>>(
        t,
        hbh[s_in], hbl[s_in], hbh[s_out], hbl[s_out],
        hf_in, hf_out,
        whh_hi, whh_lo, G0, Tg, b_hh,
        st_w, out_dyn, ln_g, ln_b, Ssem, Ssem2,
        hbh[s_ln], st_r, W1g, Psem, d1, d2, c1, c2p, hidw,
        hidr, w2bf, z_sem, b2, out_sems);
  }
}